// Round 6
// baseline (690.755 us; speedup 1.0000x reference)
//
#include <hip/hip_runtime.h>
#include <hip/hip_bf16.h>
#include <math.h>

// ---------------- problem constants ----------------
#define BATCH 4
#define NTOK  2304      // (96/2)^2
#define DIM   256
#define NHEADS 8
#define HCDIM 48
#define KSEL  345       // int(0.15 * 2304)
#define NKEEP 1959      // 2304 - 345
#define NKC   1984      // padded to 31*64
#define KT    31        // key tiles of 64
#define KREM  39        // real keys in last tile (1959 - 30*64)
#define LN_EPS 1e-5f

typedef unsigned short u16;
typedef __attribute__((ext_vector_type(8))) short bf16x8;  // 8 bf16 (4 VGPRs)
typedef __attribute__((ext_vector_type(4))) float f32x4;   // MFMA accumulator

__device__ __forceinline__ u16 f2bf(float x) {
  union { float f; unsigned u; } v; v.f = x;
  return (u16)((v.u + 0x7FFFu + ((v.u >> 16) & 1u)) >> 16);  // RNE
}

// async global->LDS, 16B per lane; lds dest = wave-uniform base + lane*16
__device__ __forceinline__ void gload_lds16(const u16* g, u16* l) {
  __builtin_amdgcn_global_load_lds((const __attribute__((address_space(1))) void*)g,
                                   (__attribute__((address_space(3))) void*)l, 16, 0, 0);
}

// ---------------- patch embed + pos (fp32) ----------------
__global__ __launch_bounds__(256) void k_patch_embed(
    const float* __restrict__ x, const float* __restrict__ pw,
    const float* __restrict__ pb, const float* __restrict__ pos,
    float* __restrict__ tokens) {
  int blk = blockIdx.x;
  int b = blk / NTOK, n = blk % NTOK;
  int hc = n / HCDIM, wc = n % HCDIM;
  __shared__ float xs[12];
  int t = threadIdx.x;
  if (t < 12) {
    int c = t >> 2, p = (t >> 1) & 1, q = t & 1;
    xs[t] = x[((b * 3 + c) * 96 + (hc * 2 + p)) * 96 + (wc * 2 + q)];
  }
  __syncthreads();
  float acc = pb[t];
#pragma unroll
  for (int i = 0; i < 12; ++i) acc += xs[i] * pw[t * 12 + i];
  tokens[(size_t)(b * NTOK + n) * DIM + t] = acc + pos[n * DIM + t];
}

// ---------------- importance MLP -> scores (fp32, exact) ----------------
__global__ __launch_bounds__(256) void k_importance(
    const float* __restrict__ tokens, const float* __restrict__ w1,
    const float* __restrict__ b1, const float* __restrict__ w2,
    const float* __restrict__ b2, float* __restrict__ scores) {
  __shared__ float ts[16 * 256];
  __shared__ float hw[16 * 256];
  int base = blockIdx.x * 16;
  int t = threadIdx.x;
  for (int i = t; i < 16 * 256; i += 256) ts[i] = tokens[(size_t)base * 256 + i];
  __syncthreads();
  float acc[16];
#pragma unroll
  for (int r = 0; r < 16; ++r) acc[r] = b1[t];
  for (int i = 0; i < 256; ++i) {
    float w = w1[i * 256 + t];
#pragma unroll
    for (int r = 0; r < 16; ++r) acc[r] += ts[r * 256 + i] * w;
  }
  float w2v = w2[t];
#pragma unroll
  for (int r = 0; r < 16; ++r) hw[r * 256 + t] = fmaxf(acc[r], 0.f) * w2v;
  __syncthreads();
  if (t < 16) {
    float s = b2[0];
    for (int i = 0; i < 256; ++i) s += hw[t * 256 + i];
    scores[base + t] = 1.f / (1.f + expf(-s));
  }
}

// ------- exact bottom-k -> compaction map, + zero Kc/VT pad regions -------
__global__ __launch_bounds__(256) void k_select(const float* __restrict__ scores,
                                                int* __restrict__ cmap,
                                                u16* __restrict__ Kc,
                                                u16* __restrict__ VT) {
  int b = blockIdx.x, t = threadIdx.x;
  __shared__ unsigned sb[NTOK];
  __shared__ int cnt;
  __shared__ int pfl[256], pfe[256];
  __shared__ int remS;
  for (int i = t; i < NTOK; i += 256) sb[i] = __float_as_uint(scores[b * NTOK + i]);
  __syncthreads();
  unsigned prefix = 0;
  int r = KSEL;
  for (int bit = 31; bit >= 0; --bit) {
    if (t == 0) cnt = 0;
    __syncthreads();
    unsigned bmask = 1u << bit;
    unsigned hmask = (bit == 31) ? 0u : ~((bmask << 1) - 1u);
    int local = 0;
    for (int i = t; i < NTOK; i += 256)
      if ((sb[i] & hmask) == prefix && !(sb[i] & bmask)) local++;
    if (local) atomicAdd(&cnt, local);
    __syncthreads();
    int c0 = cnt;
    if (r > c0) { r -= c0; prefix |= bmask; }
    __syncthreads();
  }
  unsigned v = prefix;  // exact k-th smallest bit pattern
  int cl = 0, ce = 0;
  int j0 = t * 9;
  for (int j = j0; j < j0 + 9; ++j) { cl += (sb[j] < v); ce += (sb[j] == v); }
  pfl[t] = cl; pfe[t] = ce;
  __syncthreads();
  if (t == 0) {
    int pl = 0, pe = 0;
    for (int i = 0; i < 256; ++i) {
      int a = pfl[i], e = pfe[i];
      pfl[i] = pl; pfe[i] = pe;
      pl += a; pe += e;
    }
    remS = KSEL - pl;
  }
  __syncthreads();
  int pl = pfl[t], pe = pfe[t], rem = remS;
  for (int j = j0; j < j0 + 9; ++j) {
    bool less = sb[j] < v, eq = sb[j] == v;
    bool drop = less || (eq && pe < rem);
    int dropped_before = pl + (pe < rem ? pe : rem);
    cmap[b * NTOK + j] = drop ? -1 : (j - dropped_before);
    pl += less; pe += eq;
  }
  // zero Kc pad rows (keys NKEEP..NKC-1), 256 bf16 each
  for (int i = t; i < (NKC - NKEEP) * 256; i += 256)
    Kc[((size_t)b * NKC + NKEEP) * 256 + i] = 0;
  // zero VT pad cols: 256 (h,d) rows x 25 keys
  for (int i = t; i < 256 * (NKC - NKEEP); i += 256) {
    int row = i / (NKC - NKEEP), key = i % (NKC - NKEEP);
    VT[((size_t)b * 256 + row) * NKC + NKEEP + key] = 0;
  }
}

// ---------------- fast LayerNorm -> bf16: wave per row, 4 rows/block ----------------
__global__ __launch_bounds__(256) void k_ln4bf(
    const float* __restrict__ in, u16* __restrict__ out,
    const float* __restrict__ g, const float* __restrict__ bta) {
  int w = threadIdx.x >> 6, l = threadIdx.x & 63;
  size_t row = (size_t)blockIdx.x * 4 + w;
  float4 v = *(const float4*)(in + row * DIM + l * 4);
  float s = v.x + v.y + v.z + v.w;
  float ss = v.x * v.x + v.y * v.y + v.z * v.z + v.w * v.w;
#pragma unroll
  for (int o = 1; o < 64; o <<= 1) { s += __shfl_xor(s, o); ss += __shfl_xor(ss, o); }
  float m = s * (1.f / DIM);
  float inv = rsqrtf(ss * (1.f / DIM) - m * m + LN_EPS);
  float4 gv = *(const float4*)(g + l * 4);
  float4 bv = *(const float4*)(bta + l * 4);
  union { ushort4 u4; __hip_bfloat162 h2[2]; } o4;
  o4.h2[0] = __float22bfloat162_rn(make_float2((v.x - m) * inv * gv.x + bv.x,
                                               (v.y - m) * inv * gv.y + bv.y));
  o4.h2[1] = __float22bfloat162_rn(make_float2((v.z - m) * inv * gv.z + bv.z,
                                               (v.w - m) * inv * gv.w + bv.w));
  *(ushort4*)(out + row * DIM + l * 4) = o4.u4;
}

// ---------------- fused final LayerNorm + partial token-mean ----------------
__global__ __launch_bounds__(256) void k_lnmean(
    const float* __restrict__ in, const float* __restrict__ g,
    const float* __restrict__ bta, float* __restrict__ part) {
  int chunk = blockIdx.x, b = blockIdx.y;
  int w = threadIdx.x >> 6, l = threadIdx.x & 63;
  float4 gv = *(const float4*)(g + l * 4);
  float4 bv = *(const float4*)(bta + l * 4);
  float4 acc = make_float4(0.f, 0.f, 0.f, 0.f);
  for (int i = 0; i < 16; ++i) {
    size_t row = (size_t)b * NTOK + chunk * 64 + w * 16 + i;
    float4 v = *(const float4*)(in + row * DIM + l * 4);
    float s = v.x + v.y + v.z + v.w;
    float ss = v.x * v.x + v.y * v.y + v.z * v.z + v.w * v.w;
#pragma unroll
    for (int o = 1; o < 64; o <<= 1) { s += __shfl_xor(s, o); ss += __shfl_xor(ss, o); }
    float m = s * (1.f / DIM);
    float inv = rsqrtf(ss * (1.f / DIM) - m * m + LN_EPS);
    acc.x += (v.x - m) * inv * gv.x + bv.x;
    acc.y += (v.y - m) * inv * gv.y + bv.y;
    acc.z += (v.z - m) * inv * gv.z + bv.z;
    acc.w += (v.w - m) * inv * gv.w + bv.w;
  }
  __shared__ float4 red[4][64];
  red[w][l] = acc;
  __syncthreads();
  if (w == 0) {
    float4 a0 = red[0][l], a1 = red[1][l], a2 = red[2][l], a3 = red[3][l];
    float4 tot = make_float4(a0.x + a1.x + a2.x + a3.x, a0.y + a1.y + a2.y + a3.y,
                             a0.z + a1.z + a2.z + a3.z, a0.w + a1.w + a2.w + a3.w);
    *(float4*)(part + ((size_t)b * 36 + chunk) * DIM + l * 4) = tot;
  }
}

__global__ __launch_bounds__(256) void k_mean_final(const float* __restrict__ part,
                                                    float* __restrict__ out) {
  int b = blockIdx.x, d = threadIdx.x;
  float s = 0.f;
  for (int c = 0; c < 36; ++c) s += part[(size_t)(b * 36 + c) * DIM + d];
  out[b * DIM + d] = s * (1.0f / NTOK);
}

// ---- merged weight convert + transpose: all 4 weight tensors in one dispatch ----
__global__ __launch_bounds__(256) void k_wtrans_all(
    const float* __restrict__ qkv_w, const float* __restrict__ proj_w,
    const float* __restrict__ mlp_w1, const float* __restrict__ mlp_w2,
    u16* __restrict__ wq, u16* __restrict__ wp,
    u16* __restrict__ w1, u16* __restrict__ w2) {
  int id = blockIdx.x;
  const float* W; u16* WT; int K, N, m;
  if (id < 576)       { m = id;        K = 256;  N = 768;  W = qkv_w;  WT = wq; }
  else if (id < 768)  { m = id - 576;  K = 256;  N = 256;  W = proj_w; WT = wp; }
  else if (id < 1536) { m = id - 768;  K = 256;  N = 1024; W = mlp_w1; WT = w1; }
  else                { m = id - 1536; K = 1024; N = 256;  W = mlp_w2; WT = w2; }
  int ntiles = N / 32, tilesPerLayer = ntiles * (K / 32);
  int layer = m / tilesPerLayer, tid = m % tilesPerLayer;
  int nb = (tid % ntiles) * 32, kb = (tid / ntiles) * 32;
  const float* Wl = W + (size_t)layer * K * N;
  u16* WTl = WT + (size_t)layer * K * N;
  __shared__ float tile[32][33];
  int tx = threadIdx.x & 31, ty = threadIdx.x >> 5;
  for (int i = 0; i < 32; i += 8) tile[ty + i][tx] = Wl[(size_t)(kb + ty + i) * N + nb + tx];
  __syncthreads();
  for (int i = 0; i < 32; i += 8)
    WTl[(size_t)(nb + ty + i) * K + kb + tx] = f2bf(tile[tx][ty + i]);
}

// ---------------- bf16 MFMA GEMM 128x128, dbuf async staging ----------------
__global__ __launch_bounds__(256) void k_gemm_bf16(
    const u16* __restrict__ A, const u16* __restrict__ BT,
    const float* __restrict__ bias, u16* __restrict__ outb,
    int K, int N, int act) {
  __shared__ __align__(16) u16 As[2][128 * 32];
  __shared__ __align__(16) u16 Bs[2][128 * 32];
  int t = threadIdx.x;
  int m0 = blockIdx.y * 128, n0 = blockIdx.x * 128;
  int w = t >> 6, l = t & 63, lr = l & 15, qd = l >> 4;
  int wm = (w >> 1) * 64, wn = (w & 1) * 64;
  const u16* gA = A + (size_t)(m0 + w * 16 + (l >> 2)) * K + (l & 3) * 8;
  const u16* gA2 = gA + (size_t)64 * K;
  const u16* gB = BT + (size_t)(n0 + w * 16 + (l >> 2)) * K + (l & 3) * 8;
  const u16* gB2 = gB + (size_t)64 * K;
  f32x4 acc[4][4];
#pragma unroll
  for (int i = 0; i < 4; ++i)
#pragma unroll
    for (int j = 0; j < 4; ++j)
#pragma unroll
      for (int r = 0; r < 4; ++r) acc[i][j][r] = 0.f;
  gload_lds16(gA, As[0] + w * 512);
  gload_lds16(gA2, As[0] + 2048 + w * 512);
  gload_lds16(gB, Bs[0] + w * 512);
  gload_lds16(gB2, Bs[0] + 2048 + w * 512);
  int nchunks = K >> 5;
  for (int c = 0; c < nchunks; ++c) {
    int buf = c & 1;
    __syncthreads();
    if (c + 1 < nchunks) {
      int k0 = (c + 1) << 5;
      gload_lds16(gA + k0, As[buf ^ 1] + w * 512);
      gload_lds16(gA2 + k0, As[buf ^ 1] + 2048 + w * 512);
      gload_lds16(gB + k0, Bs[buf ^ 1] + w * 512);
      gload_lds16(gB2 + k0, Bs[buf ^ 1] + 2048 + w * 512);
    }
    bf16x8 af[4], bfr[4];
#pragma unroll
    for (int mt = 0; mt < 4; ++mt)
      af[mt] = *(const bf16x8*)(As[buf] + (wm + mt * 16 + lr) * 32 + qd * 8);
#pragma unroll
    for (int nt = 0; nt < 4; ++nt)
      bfr[nt] = *(const bf16x8*)(Bs[buf] + (wn + nt * 16 + lr) * 32 + qd * 8);
#pragma unroll
    for (int mt = 0; mt < 4; ++mt)
#pragma unroll
      for (int nt = 0; nt < 4; ++nt)
        acc[mt][nt] = __builtin_amdgcn_mfma_f32_16x16x32_bf16(af[mt], bfr[nt],
                                                              acc[mt][nt], 0, 0, 0);
  }
#pragma unroll
  for (int mt = 0; mt < 4; ++mt) {
#pragma unroll
    for (int nt = 0; nt < 4; ++nt) {
#pragma unroll
      for (int r = 0; r < 4; ++r) {
        size_t m = (size_t)m0 + wm + mt * 16 + qd * 4 + r;
        int c = n0 + wn + nt * 16 + lr;
        float val = acc[mt][nt][r] + bias[c];
        if (act) val = 0.5f * val * (1.f + erff(val * 0.70710678118654752f));
        outb[m * N + c] = f2bf(val);
      }
    }
  }
}

// ------------ QKV GEMM 128x128 dbuf: Q pre-scaled (1/sqrt(32)*log2e), K->Kc, V->VT ------------
__global__ __launch_bounds__(256) void k_gemm_qkv(
    const u16* __restrict__ A, const u16* __restrict__ BT,
    const float* __restrict__ bias, const int* __restrict__ cmap,
    u16* __restrict__ Qb, u16* __restrict__ Kc, u16* __restrict__ VT) {
  const int K = 256, N = 768;
  __shared__ __align__(16) u16 As[2][128 * 32];
  __shared__ __align__(16) u16 Bs[2][128 * 32];
  int t = threadIdx.x;
  int m0 = blockIdx.y * 128, n0 = blockIdx.x * 128;
  int w = t >> 6, l = t & 63, lr = l & 15, qd = l >> 4;
  int wm = (w >> 1) * 64, wn = (w & 1) * 64;
  const u16* gA = A + (size_t)(m0 + w * 16 + (l >> 2)) * K + (l & 3) * 8;
  const u16* gA2 = gA + (size_t)64 * K;
  const u16* gB = BT + (size_t)(n0 + w * 16 + (l >> 2)) * K + (l & 3) * 8;
  const u16* gB2 = gB + (size_t)64 * K;
  f32x4 acc[4][4];
#pragma unroll
  for (int i = 0; i < 4; ++i)
#pragma unroll
    for (int j = 0; j < 4; ++j)
#pragma unroll
      for (int r = 0; r < 4; ++r) acc[i][j][r] = 0.f;
  gload_lds16(gA, As[0] + w * 512);
  gload_lds16(gA2, As[0] + 2048 + w * 512);
  gload_lds16(gB, Bs[0] + w * 512);
  gload_lds16(gB2, Bs[0] + 2048 + w * 512);
  for (int c = 0; c < 8; ++c) {
    int buf = c & 1;
    __syncthreads();
    if (c + 1 < 8) {
      int k0 = (c + 1) << 5;
      gload_lds16(gA + k0, As[buf ^ 1] + w * 512);
      gload_lds16(gA2 + k0, As[buf ^ 1] + 2048 + w * 512);
      gload_lds16(gB + k0, Bs[buf ^ 1] + w * 512);
      gload_lds16(gB2 + k0, Bs[buf ^ 1] + 2048 + w * 512);
    }
    bf16x8 af[4], bfr[4];
#pragma unroll
    for (int mt = 0; mt < 4; ++mt)
      af[mt] = *(const bf16x8*)(As[buf] + (wm + mt * 16 + lr) * 32 + qd * 8);
#pragma unroll
    for (int nt = 0; nt < 4; ++nt)
      bfr[nt] = *(const bf16x8*)(Bs[buf] + (wn + nt * 16 + lr) * 32 + qd * 8);
#pragma unroll
    for (int mt = 0; mt < 4; ++mt)
#pragma unroll
      for (int nt = 0; nt < 4; ++nt)
        acc[mt][nt] = __builtin_amdgcn_mfma_f32_16x16x32_bf16(af[mt], bfr[nt],
                                                              acc[mt][nt], 0, 0, 0);
  }
  int sec = (n0 + wn) >> 8;  // 0=Q, 1=K, 2=V (wave-uniform)
#pragma unroll
  for (int mt = 0; mt < 4; ++mt) {
#pragma unroll
    for (int r = 0; r < 4; ++r) {
      int m = m0 + wm + mt * 16 + qd * 4 + r;
      int cpos = (sec == 0) ? 0 : cmap[m];
      int b = m / NTOK;
#pragma unroll
      for (int nt = 0; nt < 4; ++nt) {
        int c = n0 + wn + nt * 16 + lr;
        float val = acc[mt][nt][r] + bias[c];
        if (sec == 0) {
          // scale folds 1/sqrt(dk) AND log2(e) (softmax via exp2)
          Qb[(size_t)m * 256 + c] = f2bf(val * 0.25508688726880056f);
        } else if (cpos >= 0) {
          if (sec == 1) {
            Kc[((size_t)b * NKC + cpos) * 256 + (c - 256)] = f2bf(val);
          } else {
            // VT[b][h=(c-512)/32][d=(c-512)%32][key=cpos]
            VT[((size_t)b * 256 + (c - 512)) * NKC + cpos] = f2bf(val);
          }
        }
      }
    }
  }
}

// ------------- bf16 MFMA GEMM 64x64 dbuf: outf = res + A @ BT^T + b -------------
// grid (N/64, M/64) -> 576 blocks for N=256 (was 288 at 128x64: half the CUs idle)
__global__ __launch_bounds__(256) void k_gemm_n64(
    const u16* __restrict__ A, const u16* __restrict__ BT,
    const float* __restrict__ bias, const float* __restrict__ res,
    float* __restrict__ outf, int K, int N) {
  __shared__ __align__(16) u16 As[2][64 * 32];
  __shared__ __align__(16) u16 Bs[2][64 * 32];
  int t = threadIdx.x;
  int m0 = blockIdx.y * 64, n0 = blockIdx.x * 64;
  int w = t >> 6, l = t & 63, lr = l & 15, qd = l >> 4;
  int wm = (w >> 1) * 32, wn = (w & 1) * 32;
  const u16* gA = A + (size_t)(m0 + w * 16 + (l >> 2)) * K + (l & 3) * 8;
  const u16* gB = BT + (size_t)(n0 + w * 16 + (l >> 2)) * K + (l & 3) * 8;
  f32x4 acc[2][2];
#pragma unroll
  for (int i = 0; i < 2; ++i)
#pragma unroll
    for (int j = 0; j < 2; ++j)
#pragma unroll
      for (int r = 0; r < 4; ++r) acc[i][j][r] = 0.f;
  gload_lds16(gA, As[0] + w * 512);
  gload_lds16(gB, Bs[0] + w * 512);
  int nchunks = K >> 5;
  for (int c = 0; c < nchunks; ++c) {
    int buf = c & 1;
    __syncthreads();
    if (c + 1 < nchunks) {
      int k0 = (c + 1) << 5;
      gload_lds16(gA + k0, As[buf ^ 1] + w * 512);
      gload_lds16(gB + k0, Bs[buf ^ 1] + w * 512);
    }
    bf16x8 af[2], bfr[2];
#pragma unroll
    for (int mt = 0; mt < 2; ++mt)
      af[mt] = *(const bf16x8*)(As[buf] + (wm + mt * 16 + lr) * 32 + qd * 8);
#pragma unroll
    for (int nt = 0; nt < 2; ++nt)
      bfr[nt] = *(const bf16x8*)(Bs[buf] + (wn + nt * 16 + lr) * 32 + qd * 8);
#pragma unroll
    for (int mt = 0; mt < 2; ++mt)
#pragma unroll
      for (int nt = 0; nt < 2; ++nt)
        acc[mt][nt] = __builtin_amdgcn_mfma_f32_16x16x32_bf16(af[mt], bfr[nt],
                                                              acc[mt][nt], 0, 0, 0);
  }
#pragma unroll
  for (int mt = 0; mt < 2; ++mt) {
#pragma unroll
    for (int nt = 0; nt < 2; ++nt) {
#pragma unroll
      for (int r = 0; r < 4; ++r) {
        size_t m = (size_t)m0 + wm + mt * 16 + qd * 4 + r;
        int c = n0 + wn + nt * 16 + lr;
        outf[m * N + c] = acc[mt][nt][r] + bias[c] + res[m * N + c];
      }
    }
  }
}

// ---------------- flash attention v5: barrier-free, wave-independent ----------------
// grid=(18,8,4), 256 thr; wave w owns 32 q rows [qt*128 + w*32, +32) (2 halves).
// Qb pre-scaled by 1/sqrt(32)*log2e. Kc: [b][1984][256] (head h at +h*32).
// VT: [b][h*32+d][1984]. Pads zeroed. No __syncthreads anywhere.
__global__ __launch_bounds__(256) void k_attn5(
    const u16* __restrict__ Qb, const u16* __restrict__ Kc,
    const u16* __restrict__ VT, u16* __restrict__ outb) {
  int qt = blockIdx.x, h = blockIdx.y, b = blockIdx.z;
  int t = threadIdx.x, w = t >> 6, l = t & 63, lr = l & 15, qd = l >> 4;
  __shared__ __align__(16) u16 Pq[4][16][80];  // per-wave P^T transpose buffer
  const short ONE = (short)0x3F80;             // bf16 1.0
  int q0 = qt * 128 + w * 32;
  const u16* kcb = Kc + (size_t)b * NKC * 256 + h * 32;
  const u16* vtb = VT + ((size_t)b * 256 + h * 32) * NKC;
  bf16x8 qf[2];
  qf[0] = *(const bf16x8*)(Qb + ((size_t)(b * NTOK) + q0 + lr) * 256 + h * 32 + qd * 8);
  qf[1] = *(const bf16x8*)(Qb + ((size_t)(b * NTOK) + q0 + 16 + lr) * 256 + h * 32 + qd * 8);
  f32x4 oa[2][2];   // [qh][dh]
  f32x4 lacc[2];    // [qh] denominators via P @ ones
#pragma unroll
  for (int r = 0; r < 4; ++r) {
    oa[0][0][r] = 0.f; oa[0][1][r] = 0.f; oa[1][0][r] = 0.f; oa[1][1][r] = 0.f;
    lacc[0][r] = 0.f; lacc[1][r] = 0.f;
  }
  bf16x8 ones;
#pragma unroll
  for (int j = 0; j < 8; ++j) ones[j] = ONE;
  // K frag: A[m=key=nt*16+lr][k=d=qd*8+j]; V frag: B[k=key][n=d=dh*16+lr]
  bf16x8 kfc[4], vfc[4], kfn[4], vfn[4];
#pragma unroll
  for (int nt = 0; nt < 4; ++nt)
    kfc[nt] = *(const bf16x8*)(kcb + (size_t)(nt * 16 + lr) * 256 + qd * 8);
#pragma unroll
  for (int kh = 0; kh < 2; ++kh)
#pragma unroll
    for (int dh = 0; dh < 2; ++dh)
      vfc[kh * 2 + dh] = *(const bf16x8*)(vtb + (size_t)(dh * 16 + lr) * NKC + kh * 32 + qd * 8);
  for (int kt = 0; kt < KT; ++kt) {
    if (kt + 1 < KT) {  // prefetch next tile (overlaps compute)
      int kb = (kt + 1) * 64;
#pragma unroll
      for (int nt = 0; nt < 4; ++nt)
        kfn[nt] = *(const bf16x8*)(kcb + (size_t)(kb + nt * 16 + lr) * 256 + qd * 8);
#pragma unroll
      for (int kh = 0; kh < 2; ++kh)
#pragma unroll
        for (int dh = 0; dh < 2; ++dh)
          vfn[kh * 2 + dh] =
              *(const bf16x8*)(vtb + (size_t)(dh * 16 + lr) * NKC + kb + kh * 32 + qd * 8);
    }
    // ones fragment masks pad keys on last tile (kh=0 keys<32<39 never masked)
    bf16x8 of1 = ones;
    if (kt == KT - 1) {
#pragma unroll
      for (int j = 0; j < 8; ++j) of1[j] = (32 + qd * 8 + j < KREM) ? ONE : (short)0;
    }
#pragma unroll
    for (int qh = 0; qh < 2; ++qh) {
      f32x4 p4[4];
#pragma unroll
      for (int nt = 0; nt < 4; ++nt) {
        f32x4 z; z[0] = 0.f; z[1] = 0.f; z[2] = 0.f; z[3] = 0.f;
        p4[nt] = __builtin_amdgcn_mfma_f32_16x16x32_bf16(kfc[nt], qf[qh], z, 0, 0, 0);
      }
#pragma unroll
      for (int nt = 0; nt < 4; ++nt)
#pragma unroll
        for (int r = 0; r < 4; ++r) p4[nt][r] = __builtin_amdgcn_exp2f(p4[nt][r]);
#pragma unroll
      for (int nt = 0; nt < 4; ++nt) {
        union { ushort4 u4; __hip_bfloat162 h2[2]; } pu;
        pu.h2[0] = __float22bfloat162_rn(make_float2(p4[nt][0], p4[nt][1]));
        pu.h2[1] = __float22bfloat162_rn(make_float2(p4[nt][2], p4[nt][3]));
        *(ushort4*)(&Pq[w][lr][nt * 16 + qd * 4]) = pu.u4;  // same-wave, no barrier
      }
#pragma unroll
      for (int kh = 0; kh < 2; ++kh) {
        bf16x8 pf = *(const bf16x8*)(&Pq[w][lr][kh * 32 + qd * 8]);
#pragma unroll
        for (int dh = 0; dh < 2; ++dh)
          oa[qh][dh] = __builtin_amdgcn_mfma_f32_16x16x32_bf16(pf, vfc[kh * 2 + dh],
                                                               oa[qh][dh], 0, 0, 0);
        lacc[qh] = __builtin_amdgcn_mfma_f32_16x16x32_bf16(pf, kh ? of1 : ones,
                                                           lacc[qh], 0, 0, 0);
      }
    }
    if (kt + 1 < KT) {
#pragma unroll
      for (int nt = 0; nt < 4; ++nt) kfc[nt] = kfn[nt];
#pragma unroll
      for (int i = 0; i < 4; ++i) vfc[i] = vfn[i];
    }
  }
#pragma unroll
  for (int qh = 0; qh < 2; ++qh) {
#pragma unroll
    for (int r = 0; r < 4; ++r) {
      float inv = 1.f / lacc[qh][r];
      size_t row = (size_t)b * NTOK + q0 + qh * 16 + qd * 4 + r;
      outb[row * 256 + h * 32 + lr] = f2bf(oa[qh][0][r] * inv);
      outb[row * 256 + h * 32 + 16 + lr] = f2bf(oa[qh][1][r] * inv);
    }
  }
}

// ---------------- driver ----------------
extern "C" void kernel_launch(void* const* d_in, const int* in_sizes, int n_in,
                              void* d_out, int out_size, void* d_ws, size_t ws_size,
                              hipStream_t stream) {
  (void)in_sizes; (void)n_in; (void)out_size;
  const float* x       = (const float*)d_in[0];
  const float* patch_w = (const float*)d_in[1];
  const float* patch_b = (const float*)d_in[2];
  const float* pos     = (const float*)d_in[3];
  const float* imp_w1  = (const float*)d_in[4];
  const float* imp_b1  = (const float*)d_in[5];
  const float* imp_w2  = (const float*)d_in[6];
  const float* imp_b2  = (const float*)d_in[7];
  const float* ln1_g   = (const float*)d_in[8];
  const float* ln1_b   = (const float*)d_in[9];
  const float* qkv_w   = (const float*)d_in[10];
  const float* qkv_b   = (const float*)d_in[11];
  const float* proj_w  = (const float*)d_in[12];
  const float* proj_b  = (const float*)d_in[13];
  const float* ln2_g   = (const float*)d_in[14];
  const float* ln2_b   = (const float*)d_in[15];
  const float* mlp_w1  = (const float*)d_in[16];
  const float* mlp_b1  = (const float*)d_in[17];
  const float* mlp_w2  = (const float*)d_in[18];
  const float* mlp_b2  = (const float*)d_in[19];
  const float* out_g   = (const float*)d_in[20];
  const float* out_b   = (const float*)d_in[21];
  float* out = (float*)d_out;

  const int M = BATCH * NTOK;                 // 9216
  const size_t TOK = (size_t)M * DIM;         // 2,359,296

  char* p = (char*)d_ws;
  float* tokens = (float*)p;       p += TOK * 4;
  float* scoresp = (float*)p;      p += (size_t)M * 4;
  int* cmap = (int*)p;             p += (size_t)M * 4;
  u16* act_bf = (u16*)p;           p += TOK * 2;
  u16* Qb = (u16*)p;               p += TOK * 2;
  u16* kc = (u16*)p;               p += (size_t)BATCH * NKC * 256 * 2;
  u16* vt = (u16*)p;               p += (size_t)BATCH * 256 * NKC * 2;
  u16* big_bf = (u16*)p;           p += (size_t)M * 1024 * 2;
  u16* wq_t = (u16*)p;             p += (size_t)3 * 768 * 256 * 2;
  u16* wp_t = (u16*)p;             p += (size_t)3 * 256 * 256 * 2;
  u16* w1_t = (u16*)p;             p += (size_t)3 * 1024 * 256 * 2;
  u16* w2_t = (u16*)p;             p += (size_t)3 * 256 * 1024 * 2;
  float* partials = (float*)act_bf;  // mean partials (act_bf dead by then)
  if (ws_size < (size_t)(p - (char*)d_ws)) return;

  k_wtrans_all<<<dim3(2304), 256, 0, stream>>>(qkv_w, proj_w, mlp_w1, mlp_w2,
                                               wq_t, wp_t, w1_t, w2_t);
  k_patch_embed<<<dim3(M), 256, 0, stream>>>(x, patch_w, patch_b, pos, tokens);
  k_importance<<<dim3(M / 16), 256, 0, stream>>>(tokens, imp_w1, imp_b1, imp_w2, imp_b2, scoresp);
  k_select<<<dim3(BATCH), 256, 0, stream>>>(scoresp, cmap, kc, vt);

  for (int l = 0; l < 3; ++l) {
    k_ln4bf<<<dim3(M / 4), 256, 0, stream>>>(tokens, act_bf, ln1_g + l * DIM, ln1_b + l * DIM);
    k_gemm_qkv<<<dim3(6, 72), 256, 0, stream>>>(
        act_bf, wq_t + (size_t)l * 768 * 256, qkv_b + l * 768, cmap, Qb, kc, vt);
    k_attn5<<<dim3(18, NHEADS, BATCH), 256, 0, stream>>>(Qb, kc, vt, act_bf);
    k_gemm_n64<<<dim3(4, 144), 256, 0, stream>>>(
        act_bf, wp_t + (size_t)l * 256 * 256, proj_b + l * DIM, tokens, tokens, 256, 256);
    k_ln4bf<<<dim3(M / 4), 256, 0, stream>>>(tokens, act_bf, ln2_g + l * DIM, ln2_b + l * DIM);
    k_gemm_bf16<<<dim3(8, 72), 256, 0, stream>>>(
        act_bf, w1_t + (size_t)l * 1024 * 256, mlp_b1 + l * 1024, big_bf, 256, 1024, 1);
    k_gemm_n64<<<dim3(4, 144), 256, 0, stream>>>(
        big_bf, w2_t + (size_t)l * 256 * 1024, mlp_b2 + l * DIM, tokens, tokens, 1024, 256);
  }
  k_lnmean<<<dim3(36, BATCH), 256, 0, stream>>>(tokens, out_g, out_b, partials);
  k_mean_final<<<dim3(BATCH), 256, 0, stream>>>(partials, out);
}

// Round 7
// 571.323 us; speedup vs baseline: 1.2090x; 1.2090x over previous
//
#include <hip/hip_runtime.h>
#include <hip/hip_bf16.h>
#include <math.h>

// ---------------- problem constants ----------------
#define BATCH 4
#define NTOK  2304      // (96/2)^2
#define DIM   256
#define NHEADS 8
#define HCDIM 48
#define KSEL  345       // int(0.15 * 2304)
#define NKEEP 1959      // 2304 - 345
#define NKC   1984      // padded to 31*64
#define KT    31        // key tiles of 64
#define KREM  39        // real keys in last tile (1959 - 30*64)
#define LN_EPS 1e-5f
// Q pre-scale: 1/sqrt(32) * log2(e)  (softmax via exp2)
#define QSCALE 0.25508688726880056f

typedef unsigned short u16;
typedef __attribute__((ext_vector_type(8))) short bf16x8;  // 8 bf16 (4 VGPRs)
typedef __attribute__((ext_vector_type(4))) float f32x4;   // MFMA accumulator

__device__ __forceinline__ u16 f2bf(float x) {
  union { float f; unsigned u; } v; v.f = x;
  return (u16)((v.u + 0x7FFFu + ((v.u >> 16) & 1u)) >> 16);  // RNE
}

// async global->LDS, 16B per lane; lds dest = wave-uniform base + lane*16
__device__ __forceinline__ void gload_lds16(const u16* g, u16* l) {
  __builtin_amdgcn_global_load_lds((const __attribute__((address_space(1))) void*)g,
                                   (__attribute__((address_space(3))) void*)l, 16, 0, 0);
}
// XOR bank swizzle: physical chunk p at row r holds logical chunk p ^ ((r>>2)&3).
// Stager (thread t, row t>>2, phys chunk t&3): load global chunk (t&3)^((t>>4)&3).
// Reader (row ..+lr, logical chunk qd): phys chunk qd^((lr>>2)&3).
// Turns the 8-way-per-phase b128 conflict into the 2-way floor (free).

// ---------------- patch embed + pos (fp32) ----------------
__global__ __launch_bounds__(256) void k_patch_embed(
    const float* __restrict__ x, const float* __restrict__ pw,
    const float* __restrict__ pb, const float* __restrict__ pos,
    float* __restrict__ tokens) {
  int blk = blockIdx.x;
  int b = blk / NTOK, n = blk % NTOK;
  int hc = n / HCDIM, wc = n % HCDIM;
  __shared__ float xs[12];
  int t = threadIdx.x;
  if (t < 12) {
    int c = t >> 2, p = (t >> 1) & 1, q = t & 1;
    xs[t] = x[((b * 3 + c) * 96 + (hc * 2 + p)) * 96 + (wc * 2 + q)];
  }
  __syncthreads();
  float acc = pb[t];
#pragma unroll
  for (int i = 0; i < 12; ++i) acc += xs[i] * pw[t * 12 + i];
  tokens[(size_t)(b * NTOK + n) * DIM + t] = acc + pos[n * DIM + t];
}

// ---------------- importance MLP -> scores (fp32, exact) ----------------
__global__ __launch_bounds__(256) void k_importance(
    const float* __restrict__ tokens, const float* __restrict__ w1,
    const float* __restrict__ b1, const float* __restrict__ w2,
    const float* __restrict__ b2, float* __restrict__ scores) {
  __shared__ float ts[16 * 256];
  __shared__ float hw[16 * 256];
  int base = blockIdx.x * 16;
  int t = threadIdx.x;
  for (int i = t; i < 16 * 256; i += 256) ts[i] = tokens[(size_t)base * 256 + i];
  __syncthreads();
  float acc[16];
#pragma unroll
  for (int r = 0; r < 16; ++r) acc[r] = b1[t];
  for (int i = 0; i < 256; ++i) {
    float w = w1[i * 256 + t];
#pragma unroll
    for (int r = 0; r < 16; ++r) acc[r] += ts[r * 256 + i] * w;
  }
  float w2v = w2[t];
#pragma unroll
  for (int r = 0; r < 16; ++r) hw[r * 256 + t] = fmaxf(acc[r], 0.f) * w2v;
  __syncthreads();
  if (t < 16) {
    float s = b2[0];
    for (int i = 0; i < 256; ++i) s += hw[t * 256 + i];
    scores[base + t] = 1.f / (1.f + expf(-s));
  }
}

// ------- exact bottom-k -> compaction map, + zero KV pad rows -------
__global__ __launch_bounds__(256) void k_select(const float* __restrict__ scores,
                                                int* __restrict__ cmap,
                                                u16* __restrict__ kvc) {
  int b = blockIdx.x, t = threadIdx.x;
  __shared__ unsigned sb[NTOK];
  __shared__ int cnt;
  __shared__ int pfl[256], pfe[256];
  __shared__ int remS;
  for (int i = t; i < NTOK; i += 256) sb[i] = __float_as_uint(scores[b * NTOK + i]);
  __syncthreads();
  unsigned prefix = 0;
  int r = KSEL;
  for (int bit = 31; bit >= 0; --bit) {
    if (t == 0) cnt = 0;
    __syncthreads();
    unsigned bmask = 1u << bit;
    unsigned hmask = (bit == 31) ? 0u : ~((bmask << 1) - 1u);
    int local = 0;
    for (int i = t; i < NTOK; i += 256)
      if ((sb[i] & hmask) == prefix && !(sb[i] & bmask)) local++;
    if (local) atomicAdd(&cnt, local);
    __syncthreads();
    int c0 = cnt;
    if (r > c0) { r -= c0; prefix |= bmask; }
    __syncthreads();
  }
  unsigned v = prefix;  // exact k-th smallest bit pattern
  int cl = 0, ce = 0;
  int j0 = t * 9;
  for (int j = j0; j < j0 + 9; ++j) { cl += (sb[j] < v); ce += (sb[j] == v); }
  pfl[t] = cl; pfe[t] = ce;
  __syncthreads();
  if (t == 0) {
    int pl = 0, pe = 0;
    for (int i = 0; i < 256; ++i) {
      int a = pfl[i], e = pfe[i];
      pfl[i] = pl; pfe[i] = pe;
      pl += a; pe += e;
    }
    remS = KSEL - pl;
  }
  __syncthreads();
  int pl = pfl[t], pe = pfe[t], rem = remS;
  for (int j = j0; j < j0 + 9; ++j) {
    bool less = sb[j] < v, eq = sb[j] == v;
    bool drop = less || (eq && pe < rem);
    int dropped_before = pl + (pe < rem ? pe : rem);
    cmap[b * NTOK + j] = drop ? -1 : (j - dropped_before);
    pl += less; pe += eq;
  }
  // zero KV pad rows (keys NKEEP..NKC-1), 512 bf16 per row
  for (int i = t; i < (NKC - NKEEP) * 512; i += 256)
    kvc[((size_t)b * NKC + NKEEP) * 512 + i] = 0;
}

// ---------------- fast LayerNorm -> bf16: wave per row, 4 rows/block ----------------
__global__ __launch_bounds__(256) void k_ln4bf(
    const float* __restrict__ in, u16* __restrict__ out,
    const float* __restrict__ g, const float* __restrict__ bta) {
  int w = threadIdx.x >> 6, l = threadIdx.x & 63;
  size_t row = (size_t)blockIdx.x * 4 + w;
  float4 v = *(const float4*)(in + row * DIM + l * 4);
  float s = v.x + v.y + v.z + v.w;
  float ss = v.x * v.x + v.y * v.y + v.z * v.z + v.w * v.w;
#pragma unroll
  for (int o = 1; o < 64; o <<= 1) { s += __shfl_xor(s, o); ss += __shfl_xor(ss, o); }
  float m = s * (1.f / DIM);
  float inv = rsqrtf(ss * (1.f / DIM) - m * m + LN_EPS);
  float4 gv = *(const float4*)(g + l * 4);
  float4 bv = *(const float4*)(bta + l * 4);
  union { ushort4 u4; __hip_bfloat162 h2[2]; } o4;
  o4.h2[0] = __float22bfloat162_rn(make_float2((v.x - m) * inv * gv.x + bv.x,
                                               (v.y - m) * inv * gv.y + bv.y));
  o4.h2[1] = __float22bfloat162_rn(make_float2((v.z - m) * inv * gv.z + bv.z,
                                               (v.w - m) * inv * gv.w + bv.w));
  *(ushort4*)(out + row * DIM + l * 4) = o4.u4;
}

// ---------------- fused final LayerNorm + partial token-mean ----------------
__global__ __launch_bounds__(256) void k_lnmean(
    const float* __restrict__ in, const float* __restrict__ g,
    const float* __restrict__ bta, float* __restrict__ part) {
  int chunk = blockIdx.x, b = blockIdx.y;
  int w = threadIdx.x >> 6, l = threadIdx.x & 63;
  float4 gv = *(const float4*)(g + l * 4);
  float4 bv = *(const float4*)(bta + l * 4);
  float4 acc = make_float4(0.f, 0.f, 0.f, 0.f);
  for (int i = 0; i < 16; ++i) {
    size_t row = (size_t)b * NTOK + chunk * 64 + w * 16 + i;
    float4 v = *(const float4*)(in + row * DIM + l * 4);
    float s = v.x + v.y + v.z + v.w;
    float ss = v.x * v.x + v.y * v.y + v.z * v.z + v.w * v.w;
#pragma unroll
    for (int o = 1; o < 64; o <<= 1) { s += __shfl_xor(s, o); ss += __shfl_xor(ss, o); }
    float m = s * (1.f / DIM);
    float inv = rsqrtf(ss * (1.f / DIM) - m * m + LN_EPS);
    acc.x += (v.x - m) * inv * gv.x + bv.x;
    acc.y += (v.y - m) * inv * gv.y + bv.y;
    acc.z += (v.z - m) * inv * gv.z + bv.z;
    acc.w += (v.w - m) * inv * gv.w + bv.w;
  }
  __shared__ float4 red[4][64];
  red[w][l] = acc;
  __syncthreads();
  if (w == 0) {
    float4 a0 = red[0][l], a1 = red[1][l], a2 = red[2][l], a3 = red[3][l];
    float4 tot = make_float4(a0.x + a1.x + a2.x + a3.x, a0.y + a1.y + a2.y + a3.y,
                             a0.z + a1.z + a2.z + a3.z, a0.w + a1.w + a2.w + a3.w);
    *(float4*)(part + ((size_t)b * 36 + chunk) * DIM + l * 4) = tot;
  }
}

__global__ __launch_bounds__(256) void k_mean_final(const float* __restrict__ part,
                                                    float* __restrict__ out) {
  int b = blockIdx.x, d = threadIdx.x;
  float s = 0.f;
  for (int c = 0; c < 36; ++c) s += part[(size_t)(b * 36 + c) * DIM + d];
  out[b * DIM + d] = s * (1.0f / NTOK);
}

// ---- merged weight convert + transpose: all 4 weight tensors in one dispatch ----
__global__ __launch_bounds__(256) void k_wtrans_all(
    const float* __restrict__ qkv_w, const float* __restrict__ proj_w,
    const float* __restrict__ mlp_w1, const float* __restrict__ mlp_w2,
    u16* __restrict__ wq, u16* __restrict__ wp,
    u16* __restrict__ w1, u16* __restrict__ w2) {
  int id = blockIdx.x;
  const float* W; u16* WT; int K, N, m;
  if (id < 576)       { m = id;        K = 256;  N = 768;  W = qkv_w;  WT = wq; }
  else if (id < 768)  { m = id - 576;  K = 256;  N = 256;  W = proj_w; WT = wp; }
  else if (id < 1536) { m = id - 768;  K = 256;  N = 1024; W = mlp_w1; WT = w1; }
  else                { m = id - 1536; K = 1024; N = 256;  W = mlp_w2; WT = w2; }
  int ntiles = N / 32, tilesPerLayer = ntiles * (K / 32);
  int layer = m / tilesPerLayer, tid = m % tilesPerLayer;
  int nb = (tid % ntiles) * 32, kb = (tid / ntiles) * 32;
  const float* Wl = W + (size_t)layer * K * N;
  u16* WTl = WT + (size_t)layer * K * N;
  __shared__ float tile[32][33];
  int tx = threadIdx.x & 31, ty = threadIdx.x >> 5;
  for (int i = 0; i < 32; i += 8) tile[ty + i][tx] = Wl[(size_t)(kb + ty + i) * N + nb + tx];
  __syncthreads();
  for (int i = 0; i < 32; i += 8)
    WTl[(size_t)(nb + ty + i) * K + kb + tx] = f2bf(tile[tx][ty + i]);
}

// ---------------- bf16 MFMA GEMM 128x128, dbuf + bank swizzle ----------------
__global__ __launch_bounds__(256) void k_gemm_bf16(
    const u16* __restrict__ A, const u16* __restrict__ BT,
    const float* __restrict__ bias, u16* __restrict__ outb,
    int K, int N, int act) {
  __shared__ __align__(16) u16 As[2][128 * 32];
  __shared__ __align__(16) u16 Bs[2][128 * 32];
  int t = threadIdx.x;
  int m0 = blockIdx.y * 128, n0 = blockIdx.x * 128;
  int w = t >> 6, l = t & 63, lr = l & 15, qd = l >> 4;
  int wm = (w >> 1) * 64, wn = (w & 1) * 64;
  int sc = ((t & 3) ^ ((t >> 4) & 3)) * 8;        // stager: swizzled global chunk
  int rc = (qd ^ ((lr >> 2) & 3)) * 8;            // reader: swizzled LDS chunk
  const u16* gA = A + (size_t)(m0 + w * 16 + (l >> 2)) * K + sc;
  const u16* gA2 = gA + (size_t)64 * K;
  const u16* gB = BT + (size_t)(n0 + w * 16 + (l >> 2)) * K + sc;
  const u16* gB2 = gB + (size_t)64 * K;
  f32x4 acc[4][4];
#pragma unroll
  for (int i = 0; i < 4; ++i)
#pragma unroll
    for (int j = 0; j < 4; ++j)
#pragma unroll
      for (int r = 0; r < 4; ++r) acc[i][j][r] = 0.f;
  gload_lds16(gA, As[0] + w * 512);
  gload_lds16(gA2, As[0] + 2048 + w * 512);
  gload_lds16(gB, Bs[0] + w * 512);
  gload_lds16(gB2, Bs[0] + 2048 + w * 512);
  int nchunks = K >> 5;
  for (int c = 0; c < nchunks; ++c) {
    int buf = c & 1;
    __syncthreads();
    if (c + 1 < nchunks) {
      int k0 = (c + 1) << 5;
      gload_lds16(gA + k0, As[buf ^ 1] + w * 512);
      gload_lds16(gA2 + k0, As[buf ^ 1] + 2048 + w * 512);
      gload_lds16(gB + k0, Bs[buf ^ 1] + w * 512);
      gload_lds16(gB2 + k0, Bs[buf ^ 1] + 2048 + w * 512);
    }
    bf16x8 af[4], bfr[4];
#pragma unroll
    for (int mt = 0; mt < 4; ++mt)
      af[mt] = *(const bf16x8*)(As[buf] + (wm + mt * 16 + lr) * 32 + rc);
#pragma unroll
    for (int nt = 0; nt < 4; ++nt)
      bfr[nt] = *(const bf16x8*)(Bs[buf] + (wn + nt * 16 + lr) * 32 + rc);
#pragma unroll
    for (int mt = 0; mt < 4; ++mt)
#pragma unroll
      for (int nt = 0; nt < 4; ++nt)
        acc[mt][nt] = __builtin_amdgcn_mfma_f32_16x16x32_bf16(af[mt], bfr[nt],
                                                              acc[mt][nt], 0, 0, 0);
  }
#pragma unroll
  for (int mt = 0; mt < 4; ++mt) {
#pragma unroll
    for (int nt = 0; nt < 4; ++nt) {
#pragma unroll
      for (int r = 0; r < 4; ++r) {
        size_t m = (size_t)m0 + wm + mt * 16 + qd * 4 + r;
        int c = n0 + wn + nt * 16 + lr;
        float val = acc[mt][nt][r] + bias[c];
        if (act) val = 0.5f * val * (1.f + erff(val * 0.70710678118654752f));
        outb[m * N + c] = f2bf(val);
      }
    }
  }
}

// ------------ QKV GEMM 128x128 dbuf+swizzle: Q scaled (exp2-fold), KV compacted ------------
__global__ __launch_bounds__(256) void k_gemm_qkv(
    const u16* __restrict__ A, const u16* __restrict__ BT,
    const float* __restrict__ bias, const int* __restrict__ cmap,
    u16* __restrict__ Qb, u16* __restrict__ KVc) {
  const int K = 256, N = 768;
  __shared__ __align__(16) u16 As[2][128 * 32];
  __shared__ __align__(16) u16 Bs[2][128 * 32];
  int t = threadIdx.x;
  int m0 = blockIdx.y * 128, n0 = blockIdx.x * 128;
  int w = t >> 6, l = t & 63, lr = l & 15, qd = l >> 4;
  int wm = (w >> 1) * 64, wn = (w & 1) * 64;
  int sc = ((t & 3) ^ ((t >> 4) & 3)) * 8;
  int rc = (qd ^ ((lr >> 2) & 3)) * 8;
  const u16* gA = A + (size_t)(m0 + w * 16 + (l >> 2)) * K + sc;
  const u16* gA2 = gA + (size_t)64 * K;
  const u16* gB = BT + (size_t)(n0 + w * 16 + (l >> 2)) * K + sc;
  const u16* gB2 = gB + (size_t)64 * K;
  f32x4 acc[4][4];
#pragma unroll
  for (int i = 0; i < 4; ++i)
#pragma unroll
    for (int j = 0; j < 4; ++j)
#pragma unroll
      for (int r = 0; r < 4; ++r) acc[i][j][r] = 0.f;
  gload_lds16(gA, As[0] + w * 512);
  gload_lds16(gA2, As[0] + 2048 + w * 512);
  gload_lds16(gB, Bs[0] + w * 512);
  gload_lds16(gB2, Bs[0] + 2048 + w * 512);
  for (int c = 0; c < 8; ++c) {
    int buf = c & 1;
    __syncthreads();
    if (c + 1 < 8) {
      int k0 = (c + 1) << 5;
      gload_lds16(gA + k0, As[buf ^ 1] + w * 512);
      gload_lds16(gA2 + k0, As[buf ^ 1] + 2048 + w * 512);
      gload_lds16(gB + k0, Bs[buf ^ 1] + w * 512);
      gload_lds16(gB2 + k0, Bs[buf ^ 1] + 2048 + w * 512);
    }
    bf16x8 af[4], bfr[4];
#pragma unroll
    for (int mt = 0; mt < 4; ++mt)
      af[mt] = *(const bf16x8*)(As[buf] + (wm + mt * 16 + lr) * 32 + rc);
#pragma unroll
    for (int nt = 0; nt < 4; ++nt)
      bfr[nt] = *(const bf16x8*)(Bs[buf] + (wn + nt * 16 + lr) * 32 + rc);
#pragma unroll
    for (int mt = 0; mt < 4; ++mt)
#pragma unroll
      for (int nt = 0; nt < 4; ++nt)
        acc[mt][nt] = __builtin_amdgcn_mfma_f32_16x16x32_bf16(af[mt], bfr[nt],
                                                              acc[mt][nt], 0, 0, 0);
  }
  bool isQ = (n0 + wn) < 256;  // wave-uniform (64-col wave span never crosses 256)
#pragma unroll
  for (int mt = 0; mt < 4; ++mt) {
#pragma unroll
    for (int r = 0; r < 4; ++r) {
      int m = m0 + wm + mt * 16 + qd * 4 + r;
      int cpos = isQ ? 0 : cmap[m];
      int b = m / NTOK;
#pragma unroll
      for (int nt = 0; nt < 4; ++nt) {
        int c = n0 + wn + nt * 16 + lr;
        float val = acc[mt][nt][r] + bias[c];
        if (isQ) {
          Qb[(size_t)m * 256 + c] = f2bf(val * QSCALE);
        } else if (cpos >= 0) {
          KVc[((size_t)b * NKC + cpos) * 512 + (c - 256)] = f2bf(val);
        }
      }
    }
  }
}

// ------------- bf16 MFMA GEMM 64x64 dbuf+swizzle: outf = res + A @ BT^T + b -------------
__global__ __launch_bounds__(256) void k_gemm_n64(
    const u16* __restrict__ A, const u16* __restrict__ BT,
    const float* __restrict__ bias, const float* __restrict__ res,
    float* __restrict__ outf, int K, int N) {
  __shared__ __align__(16) u16 As[2][64 * 32];
  __shared__ __align__(16) u16 Bs[2][64 * 32];
  int t = threadIdx.x;
  int m0 = blockIdx.y * 64, n0 = blockIdx.x * 64;
  int w = t >> 6, l = t & 63, lr = l & 15, qd = l >> 4;
  int wm = (w >> 1) * 32, wn = (w & 1) * 32;
  int sc = ((t & 3) ^ ((t >> 4) & 3)) * 8;
  int rc = (qd ^ ((lr >> 2) & 3)) * 8;
  const u16* gA = A + (size_t)(m0 + w * 16 + (l >> 2)) * K + sc;
  const u16* gB = BT + (size_t)(n0 + w * 16 + (l >> 2)) * K + sc;
  f32x4 acc[2][2];
#pragma unroll
  for (int i = 0; i < 2; ++i)
#pragma unroll
    for (int j = 0; j < 2; ++j)
#pragma unroll
      for (int r = 0; r < 4; ++r) acc[i][j][r] = 0.f;
  gload_lds16(gA, As[0] + w * 512);
  gload_lds16(gB, Bs[0] + w * 512);
  int nchunks = K >> 5;
  for (int c = 0; c < nchunks; ++c) {
    int buf = c & 1;
    __syncthreads();
    if (c + 1 < nchunks) {
      int k0 = (c + 1) << 5;
      gload_lds16(gA + k0, As[buf ^ 1] + w * 512);
      gload_lds16(gB + k0, Bs[buf ^ 1] + w * 512);
    }
    bf16x8 af[2], bfr[2];
#pragma unroll
    for (int mt = 0; mt < 2; ++mt)
      af[mt] = *(const bf16x8*)(As[buf] + (wm + mt * 16 + lr) * 32 + rc);
#pragma unroll
    for (int nt = 0; nt < 2; ++nt)
      bfr[nt] = *(const bf16x8*)(Bs[buf] + (wn + nt * 16 + lr) * 32 + rc);
#pragma unroll
    for (int mt = 0; mt < 2; ++mt)
#pragma unroll
      for (int nt = 0; nt < 2; ++nt)
        acc[mt][nt] = __builtin_amdgcn_mfma_f32_16x16x32_bf16(af[mt], bfr[nt],
                                                              acc[mt][nt], 0, 0, 0);
  }
#pragma unroll
  for (int mt = 0; mt < 2; ++mt) {
#pragma unroll
    for (int nt = 0; nt < 2; ++nt) {
#pragma unroll
      for (int r = 0; r < 4; ++r) {
        size_t m = (size_t)m0 + wm + mt * 16 + qd * 4 + r;
        int c = n0 + wn + nt * 16 + lr;
        outf[m * N + c] = acc[mt][nt][r] + bias[c] + res[m * N + c];
      }
    }
  }
}

// ------- flash attention v6: attn3 structure + K swizzle + exp2 + l-via-MFMA -------
// grid=(36,8,4), 256 thr; wave w owns q rows [qt*64 + w*16, +16).
// Qb pre-scaled by QSCALE. KVc: [b][1984][512] (K|V, head h at +h*32), pads zeroed.
__global__ __launch_bounds__(256) void k_attn6(
    const u16* __restrict__ Qb, const u16* __restrict__ KVc,
    u16* __restrict__ outb) {
  int qt = blockIdx.x, h = blockIdx.y, b = blockIdx.z;
  int t = threadIdx.x, w = t >> 6, l = t & 63, lr = l & 15, qd = l >> 4;
  __shared__ __align__(16) u16 Ks[2][64 * 32];   // [buf][key][d], XOR-swizzled chunks
  __shared__ __align__(16) u16 Vt[2][32][72];    // [buf][d][key] (2-way banks: free)
  __shared__ __align__(16) u16 Pq[4][16][72];    // per-wave P^T [q][key]
  const short ONE = (short)0x3F80;               // bf16 1.0
  int q0 = qt * 64 + w * 16;
  bf16x8 qf = *(const bf16x8*)(Qb + ((size_t)(b * NTOK) + q0 + lr) * 256 + h * 32 + qd * 8);
  const u16* kvb = KVc + (size_t)b * NKC * 512;
  // K stager: thread t -> key t>>2, swizzled d-chunk (t&3)^((t>>4)&3)
  const u16* gK = kvb + (size_t)(t >> 2) * 512 + h * 32 + ((t & 3) ^ ((t >> 4) & 3)) * 8;
  // V stager: wave w -> d rows [w*8,+8), key = l (transposed LDS write, conflict-free)
  const u16* gV = kvb + (size_t)l * 512 + 256 + h * 32 + w * 8;
  int rc = (qd ^ ((lr >> 2) & 3)) * 8;           // swizzled reader chunk
  gload_lds16(gK, &Ks[0][w * 512]);
  bf16x8 vr = *(const bf16x8*)(gV);
  f32x4 oa[2];   // [dh]
  f32x4 lacc;    // denominators via P @ ones (C-layout: every lane holds its row's l)
#pragma unroll
  for (int r = 0; r < 4; ++r) { oa[0][r] = 0.f; oa[1][r] = 0.f; lacc[r] = 0.f; }
  bf16x8 ones;
#pragma unroll
  for (int j = 0; j < 8; ++j) ones[j] = ONE;
  for (int kt = 0; kt < KT; ++kt) {
    int buf = kt & 1;
#pragma unroll
    for (int j = 0; j < 8; ++j) Vt[buf][w * 8 + j][l] = (u16)vr[j];
    __syncthreads();  // Ks[buf] async done + Vt[buf] visible; prev tile consumed
    if (kt + 1 < KT) {
      size_t off = (size_t)(kt + 1) * 64 * 512;
      gload_lds16(gK + off, &Ks[buf ^ 1][w * 512]);
      vr = *(const bf16x8*)(gV + off);
    }
    // S^T = K Q^T (exp2 domain: Q pre-scaled by log2e/sqrt(dk))
    f32x4 p4[4];
#pragma unroll
    for (int nt = 0; nt < 4; ++nt) {
      bf16x8 kf = *(const bf16x8*)(&Ks[buf][(nt * 16 + lr) * 32 + rc]);
      f32x4 z; z[0] = 0.f; z[1] = 0.f; z[2] = 0.f; z[3] = 0.f;
      p4[nt] = __builtin_amdgcn_mfma_f32_16x16x32_bf16(kf, qf, z, 0, 0, 0);
    }
#pragma unroll
    for (int nt = 0; nt < 4; ++nt)
#pragma unroll
      for (int r = 0; r < 4; ++r) p4[nt][r] = __builtin_amdgcn_exp2f(p4[nt][r]);
    // store P^T -> Pq[w][q=lr][key], 4 packed b64 writes (same-wave, no barrier)
#pragma unroll
    for (int nt = 0; nt < 4; ++nt) {
      union { ushort4 u4; __hip_bfloat162 h2[2]; } pu;
      pu.h2[0] = __float22bfloat162_rn(make_float2(p4[nt][0], p4[nt][1]));
      pu.h2[1] = __float22bfloat162_rn(make_float2(p4[nt][2], p4[nt][3]));
      *(ushort4*)(&Pq[w][lr][nt * 16 + qd * 4]) = pu.u4;
    }
    // ones fragment masks pad keys on last tile (kh=0 keys<32<39 never masked);
    // V pad rows are zero, so O needs no masking.
    bf16x8 of1 = ones;
    if (kt == KT - 1) {
#pragma unroll
      for (int j = 0; j < 8; ++j) of1[j] = (32 + qd * 8 + j < KREM) ? ONE : (short)0;
    }
    // O += P V ;  l += P 1
#pragma unroll
    for (int kh = 0; kh < 2; ++kh) {
      bf16x8 pf = *(const bf16x8*)(&Pq[w][lr][kh * 32 + qd * 8]);
#pragma unroll
      for (int dh = 0; dh < 2; ++dh) {
        bf16x8 vf = *(const bf16x8*)(&Vt[buf][dh * 16 + lr][kh * 32 + qd * 8]);
        oa[dh] = __builtin_amdgcn_mfma_f32_16x16x32_bf16(pf, vf, oa[dh], 0, 0, 0);
      }
      lacc = __builtin_amdgcn_mfma_f32_16x16x32_bf16(pf, kh ? of1 : ones, lacc, 0, 0, 0);
    }
  }
#pragma unroll
  for (int r = 0; r < 4; ++r) {
    float inv = 1.f / lacc[r];
    size_t row = (size_t)b * NTOK + q0 + qd * 4 + r;
    outb[row * 256 + h * 32 + lr] = f2bf(oa[0][r] * inv);
    outb[row * 256 + h * 32 + 16 + lr] = f2bf(oa[1][r] * inv);
  }
}

// ---------------- driver ----------------
extern "C" void kernel_launch(void* const* d_in, const int* in_sizes, int n_in,
                              void* d_out, int out_size, void* d_ws, size_t ws_size,
                              hipStream_t stream) {
  (void)in_sizes; (void)n_in; (void)out_size;
  const float* x       = (const float*)d_in[0];
  const float* patch_w = (const float*)d_in[1];
  const float* patch_b = (const float*)d_in[2];
  const float* pos     = (const float*)d_in[3];
  const float* imp_w1  = (const float*)d_in[4];
  const float* imp_b1  = (const float*)d_in[5];
  const float* imp_w2  = (const float*)d_in[6];
  const float* imp_b2  = (const float*)d_in[7];
  const float* ln1_g   = (const float*)d_in[8];
  const float* ln1_b   = (const float*)d_in[9];
  const float* qkv_w   = (const float*)d_in[10];
  const float* qkv_b   = (const float*)d_in[11];
  const float* proj_w  = (const float*)d_in[12];
  const float* proj_b  = (const float*)d_in[13];
  const float* ln2_g   = (const float*)d_in[14];
  const float* ln2_b   = (const float*)d_in[15];
  const float* mlp_w1  = (const float*)d_in[16];
  const float* mlp_b1  = (const float*)d_in[17];
  const float* mlp_w2  = (const float*)d_in[18];
  const float* mlp_b2  = (const float*)d_in[19];
  const float* out_g   = (const float*)d_in[20];
  const float* out_b   = (const float*)d_in[21];
  float* out = (float*)d_out;

  const int M = BATCH * NTOK;                 // 9216
  const size_t TOK = (size_t)M * DIM;         // 2,359,296

  char* p = (char*)d_ws;
  float* tokens = (float*)p;       p += TOK * 4;
  float* scoresp = (float*)p;      p += (size_t)M * 4;
  int* cmap = (int*)p;             p += (size_t)M * 4;
  u16* act_bf = (u16*)p;           p += TOK * 2;
  u16* Qb = (u16*)p;               p += TOK * 2;
  u16* kvc = (u16*)p;              p += (size_t)BATCH * NKC * 512 * 2;
  u16* big_bf = (u16*)p;           p += (size_t)M * 1024 * 2;
  u16* wq_t = (u16*)p;             p += (size_t)3 * 768 * 256 * 2;
  u16* wp_t = (u16*)p;             p += (size_t)3 * 256 * 256 * 2;
  u16* w1_t = (u16*)p;             p += (size_t)3 * 1024 * 256 * 2;
  u16* w2_t = (u16*)p;             p += (size_t)3 * 256 * 1024 * 2;
  float* partials = (float*)act_bf;  // mean partials (act_bf dead by then)
  if (ws_size < (size_t)(p - (char*)d_ws)) return;

  k_wtrans_all<<<dim3(2304), 256, 0, stream>>>(qkv_w, proj_w, mlp_w1, mlp_w2,
                                               wq_t, wp_t, w1_t, w2_t);
  k_patch_embed<<<dim3(M), 256, 0, stream>>>(x, patch_w, patch_b, pos, tokens);
  k_importance<<<dim3(M / 16), 256, 0, stream>>>(tokens, imp_w1, imp_b1, imp_w2, imp_b2, scoresp);
  k_select<<<dim3(BATCH), 256, 0, stream>>>(scoresp, cmap, kvc);

  for (int l = 0; l < 3; ++l) {
    k_ln4bf<<<dim3(M / 4), 256, 0, stream>>>(tokens, act_bf, ln1_g + l * DIM, ln1_b + l * DIM);
    k_gemm_qkv<<<dim3(6, 72), 256, 0, stream>>>(
        act_bf, wq_t + (size_t)l * 768 * 256, qkv_b + l * 768, cmap, Qb, kvc);
    k_attn6<<<dim3(36, NHEADS, BATCH), 256, 0, stream>>>(Qb, kvc, act_bf);
    k_gemm_n64<<<dim3(4, 144), 256, 0, stream>>>(
        act_bf, wp_t + (size_t)l * 256 * 256, proj_b + l * DIM, tokens, tokens, 256, 256);
    k_ln4bf<<<dim3(M / 4), 256, 0, stream>>>(tokens, act_bf, ln2_g + l * DIM, ln2_b + l * DIM);
    k_gemm_bf16<<<dim3(8, 72), 256, 0, stream>>>(
        act_bf, w1_t + (size_t)l * 1024 * 256, mlp_b1 + l * 1024, big_bf, 256, 1024, 1);
    k_gemm_n64<<<dim3(4, 144), 256, 0, stream>>>(
        big_bf, w2_t + (size_t)l * 256 * 1024, mlp_b2 + l * DIM, tokens, tokens, 1024, 256);
  }
  k_lnmean<<<dim3(36, BATCH), 256, 0, stream>>>(tokens, out_g, out_b, partials);
  k_mean_final<<<dim3(BATCH), 256, 0, stream>>>(partials, out);
}